// Round 1
// baseline (3367.681 us; speedup 1.0000x reference)
//
#include <hip/hip_runtime.h>
#include <hip/hip_bf16.h>
#include <cmath>

// Problem constants (from reference file)
#define BATCH 16384
#define N_NBR 50
#define H_DIM 128

typedef __attribute__((ext_vector_type(8))) short short8;
typedef __attribute__((ext_vector_type(4))) float float4v;

__device__ inline short f2bf(float f) {
    // round-to-nearest-even fp32 -> bf16 (inputs are finite)
    unsigned int u = __builtin_bit_cast(unsigned int, f);
    u += 0x7FFFu + ((u >> 16) & 1u);
    return (short)(u >> 16);
}

// Pre-convert the three W matrices to bf16 and precompute b+u, into d_ws.
// ws layout: shorts [0,81920): W_user(16384) | W_news(16384) | W_sem(49152)
//            floats at byte offset 163840: bu_user(128)|bu_news(128)|bu_sem(128)
__global__ void prep_kernel(const float* __restrict__ Wu, const float* __restrict__ Wn,
                            const float* __restrict__ Ws,
                            const float* __restrict__ bu_, const float* __restrict__ uu_,
                            const float* __restrict__ bn_, const float* __restrict__ un_,
                            const float* __restrict__ bs_, const float* __restrict__ us_,
                            short* __restrict__ Wbf, float* __restrict__ buv)
{
    int i = blockIdx.x * blockDim.x + threadIdx.x;
    if (i < 16384)       Wbf[i] = f2bf(Wu[i]);
    else if (i < 32768)  Wbf[i] = f2bf(Wn[i - 16384]);
    else if (i < 81920)  Wbf[i] = f2bf(Ws[i - 32768]);
    if (i < 128)         buv[i] = bu_[i] + uu_[i];
    else if (i < 256)    buv[i] = bn_[i - 128] + un_[i - 128];
    else if (i < 384)    buv[i] = bs_[i - 256] + us_[i - 256];
}

// One block per batch row. 4 waves; wave w owns M-rows [16w, 16w+16).
// C[n][h] = sum_k x[n][k] * W[h][k]  via mfma_f32_16x16x32_bf16.
// A-frag: A[m=lane&15][k=quad*8+j]; B-frag: B[k=quad*8+j][n=lane&15];
// C/D: col=lane&15, row=quad*4+reg   [per guide §3, m89-verified]
template<int D>
__global__ __launch_bounds__(256)
void agg_kernel(const float* __restrict__ x, const int* __restrict__ mask,
                const short* __restrict__ Wbf, const float* __restrict__ buv,
                const float* __restrict__ q, float* __restrict__ out)
{
    const int b    = blockIdx.x;
    const int tid  = threadIdx.x;
    const int lane = tid & 63;
    const int wv   = tid >> 6;
    const int mrow = lane & 15;   // A row / C col index within tile
    const int kgrp = lane >> 4;   // 0..3

    __shared__ float s_scores[64];
    __shared__ float s_attn[64];

    // ---- Phase 1: h-matmul via MFMA ----
    const int  n_row  = wv * 16 + mrow;
    const bool row_ok = (n_row < N_NBR);
    const float* xrow = x + ((size_t)b * N_NBR + n_row) * D;

    float4v acc[8];
#pragma unroll
    for (int t = 0; t < 8; ++t) acc[t] = (float4v){0.f, 0.f, 0.f, 0.f};

    for (int kk = 0; kk < D / 32; ++kk) {
        short8 a;
        if (row_ok) {
            const float* p = xrow + kk * 32 + kgrp * 8;
            float4v x0 = *(const float4v*)p;
            float4v x1 = *(const float4v*)(p + 4);
#pragma unroll
            for (int j = 0; j < 4; ++j) { a[j] = f2bf(x0[j]); a[j + 4] = f2bf(x1[j]); }
        } else {
            a = (short8){0, 0, 0, 0, 0, 0, 0, 0};
        }
#pragma unroll
        for (int ht = 0; ht < 8; ++ht) {
            const short* wp = Wbf + (size_t)(ht * 16 + mrow) * D + kk * 32 + kgrp * 8;
            short8 bf = *(const short8*)wp;   // 16B aligned: k offset multiple of 8 shorts
            acc[ht] = __builtin_amdgcn_mfma_f32_16x16x32_bf16(a, bf, acc[ht], 0, 0, 0);
        }
    }

    // ---- Phase 1.5: tanh + dot(q) -> scores ----
    float s_part[4] = {0.f, 0.f, 0.f, 0.f};
#pragma unroll
    for (int ht = 0; ht < 8; ++ht) {
        int h = ht * 16 + mrow;
        float bu = buv[h];
        float qh = q[h];
#pragma unroll
        for (int r = 0; r < 4; ++r) {
            float hv = tanhf(acc[ht][r] + bu);
            s_part[r] += qh * hv;
        }
    }
    // reduce across the 16 lanes of each quad (xor bits 0..3 stays in-quad)
#pragma unroll
    for (int off = 1; off < 16; off <<= 1) {
#pragma unroll
        for (int r = 0; r < 4; ++r) s_part[r] += __shfl_xor(s_part[r], off, 64);
    }
    if (mrow == 0) {
#pragma unroll
        for (int r = 0; r < 4; ++r) s_scores[wv * 16 + kgrp * 4 + r] = s_part[r];
    }
    __syncthreads();

    // ---- Phase 2: masked softmax over N (wave 0) ----
    if (wv == 0) {
        int n = lane;
        bool valid = (n < N_NBR) && (mask[(size_t)b * N_NBR + n] != 0);
        float s = valid ? s_scores[n] : -INFINITY;
        float mx = s;
#pragma unroll
        for (int off = 1; off < 64; off <<= 1) mx = fmaxf(mx, __shfl_xor(mx, off, 64));
        float e = valid ? expf(s - mx) : 0.f;
        float sum = e;
#pragma unroll
        for (int off = 1; off < 64; off <<= 1) sum += __shfl_xor(sum, off, 64);
        s_attn[n] = e / sum;
    }
    __syncthreads();

    // ---- Phase 3: attn-weighted sum (fp32, coalesced) ----
    for (int d = tid; d < D; d += 256) {
        float a = 0.f;
        const float* xb = x + (size_t)b * N_NBR * D + d;
#pragma unroll 5
        for (int n = 0; n < N_NBR; ++n) a += s_attn[n] * xb[(size_t)n * D];
        out[(size_t)b * D + d] = a;
    }
}

extern "C" void kernel_launch(void* const* d_in, const int* in_sizes, int n_in,
                              void* d_out, int out_size, void* d_ws, size_t ws_size,
                              hipStream_t stream)
{
    const float* xu = (const float*)d_in[0];   // (B,50,128)
    const float* xn = (const float*)d_in[1];   // (B,50,128)
    const float* xs = (const float*)d_in[2];   // (B,50,384)
    const int*   mu = (const int*)d_in[3];     // (B,50) bool -> int32
    const int*   mn = (const int*)d_in[4];     // (B,50) bool -> int32
    const float* Wu = (const float*)d_in[5];
    const float* bu = (const float*)d_in[6];
    const float* uu = (const float*)d_in[7];
    const float* qu = (const float*)d_in[8];
    const float* Wn = (const float*)d_in[9];
    const float* bn = (const float*)d_in[10];
    const float* un = (const float*)d_in[11];
    const float* qn = (const float*)d_in[12];
    const float* Ws = (const float*)d_in[13];
    const float* bs = (const float*)d_in[14];
    const float* us = (const float*)d_in[15];
    const float* qs = (const float*)d_in[16];

    short* Wbf = (short*)d_ws;                          // 81920 shorts
    float* buv = (float*)((char*)d_ws + 163840);        // 384 floats

    prep_kernel<<<320, 256, 0, stream>>>(Wu, Wn, Ws, bu, uu, bn, un, bs, us, Wbf, buv);

    float* out = (float*)d_out;
    agg_kernel<128><<<BATCH, 256, 0, stream>>>(xu, mu, Wbf,          buv,        qu, out);
    agg_kernel<128><<<BATCH, 256, 0, stream>>>(xn, mn, Wbf + 16384,  buv + 128,  qn, out + (size_t)BATCH * 128);
    agg_kernel<384><<<BATCH, 256, 0, stream>>>(xs, mn, Wbf + 32768,  buv + 256,  qs, out + (size_t)BATCH * 256);
}